// Round 2
// baseline (6523.812 us; speedup 1.0000x reference)
//
#include <hip/hip_runtime.h>
#include <hip/hip_bf16.h>

#define B_ 64
#define T_ 512
#define H_ 1024
#define G_ 3072
#define M_ (B_ * T_)

typedef __attribute__((ext_vector_type(8))) short bf16x8;
typedef __attribute__((ext_vector_type(4))) float f32x4;

__device__ __forceinline__ unsigned short f2bf(float x) {
  __hip_bfloat16 h = __float2bfloat16(x);  // RNE
  return *reinterpret_cast<unsigned short*>(&h);
}
__device__ __forceinline__ float bf2f(unsigned short u) {
  __hip_bfloat16 h;
  *reinterpret_cast<unsigned short*>(&h) = u;
  return __bfloat162float(h);
}

// ---------------------------------------------------------------- cvt fp32->bf16
__global__ __launch_bounds__(256) void cvt_f32_to_bf16(const float* __restrict__ src,
                                                       unsigned short* __restrict__ dst,
                                                       long n) {
  long i = ((long)blockIdx.x * 256 + threadIdx.x) * 4;
  if (i + 4 <= n) {
    float4 v = *(const float4*)(src + i);
    ushort4 o;
    o.x = f2bf(v.x); o.y = f2bf(v.y); o.z = f2bf(v.z); o.w = f2bf(v.w);
    *(ushort4*)(dst + i) = o;
  }
}

// ---------------------------------------------------------------- gi = A @ W^T + b (NT GEMM, bf16 in, bf16 out)
// A: [M,K] bf16 row-major, Bw: [N,K] bf16 row-major, C: [M,N] bf16, bias fp32 [N]
// 128x128 tile, BK=64, 4 waves (2x2), m97-style global_load_lds staging.
__global__ __launch_bounds__(256) void gemm_nt_bf16(const unsigned short* __restrict__ A,
                                                    const unsigned short* __restrict__ Bw,
                                                    const float* __restrict__ bias,
                                                    unsigned short* __restrict__ C) {
  constexpr int BM = 128, BN = 128, BK = 64;
  constexpr int K = H_, N = G_;
  __shared__ unsigned short As[BM * BK];
  __shared__ unsigned short Bs[BN * BK];
  const int nbn = N / BN;  // 24
  const int bn = blockIdx.x % nbn;
  const int bm = blockIdx.x / nbn;
  const int tid = threadIdx.x;
  const int wave = tid >> 6;
  const int lane = tid & 63;
  const int l15 = lane & 15, l4 = lane >> 4;
  const int wr = wave >> 1, wc = wave & 1;

  const long a0 = (long)bm * BM;
  const long b0 = (long)bn * BN;

  f32x4 acc[4][4] = {};

  const int srow = tid >> 3;  // 0..31
  const int schk = tid & 7;   // 0..7

  for (int k0 = 0; k0 < K; k0 += BK) {
#pragma unroll
    for (int r = 0; r < 4; ++r) {
      int row = r * 32 + srow;
      const unsigned short* ga = A + (a0 + row) * K + k0 + schk * 8;
      const unsigned short* gb = Bw + (b0 + row) * K + k0 + schk * 8;
      // LDS dest is wave-uniform base + lane*16 (linear layout, no swizzle).
      char* la = (char*)As + r * 4096 + wave * 1024;
      char* lb = (char*)Bs + r * 4096 + wave * 1024;
      __builtin_amdgcn_global_load_lds((const __attribute__((address_space(1))) void*)ga,
                                       (__attribute__((address_space(3))) void*)la, 16, 0, 0);
      __builtin_amdgcn_global_load_lds((const __attribute__((address_space(1))) void*)gb,
                                       (__attribute__((address_space(3))) void*)lb, 16, 0, 0);
    }
    __syncthreads();  // compiler emits vmcnt(0) drain before s_barrier
#pragma unroll
    for (int kk = 0; kk < BK; kk += 32) {
      bf16x8 af[4], bfr[4];
#pragma unroll
      for (int i = 0; i < 4; ++i)
        af[i] = *(const bf16x8*)&As[(wr * 64 + i * 16 + l15) * BK + kk + l4 * 8];
#pragma unroll
      for (int j = 0; j < 4; ++j)
        bfr[j] = *(const bf16x8*)&Bs[(wc * 64 + j * 16 + l15) * BK + kk + l4 * 8];
#pragma unroll
      for (int i = 0; i < 4; ++i)
#pragma unroll
        for (int j = 0; j < 4; ++j)
          acc[i][j] = __builtin_amdgcn_mfma_f32_16x16x32_bf16(af[i], bfr[j], acc[i][j], 0, 0, 0);
    }
    __syncthreads();
  }
  // epilogue: C/D layout col=lane&15, row=(lane>>4)*4+reg  [measured: m89/m91]
#pragma unroll
  for (int j = 0; j < 4; ++j) {
    int col = (int)b0 + wc * 64 + j * 16 + l15;
    float bv = bias[col];
#pragma unroll
    for (int i = 0; i < 4; ++i) {
      long row = a0 + wr * 64 + i * 16 + l4 * 4;
#pragma unroll
      for (int r2 = 0; r2 < 4; ++r2) {
        C[(row + r2) * N + col] = f2bf(acc[i][j][r2] + bv);
      }
    }
  }
}

// ---------------------------------------------------------------- one GRU timestep
// 256 blocks x 256 threads. Block owns 4 hidden cols (c0 = blk*4) -> 12 gate rows.
// Wave w computes gh[batches w*16..w*16+15][12 gate cols] via MFMA.
// 4 independent accumulators break the serial MFMA dependency chain.
__global__ __launch_bounds__(256) void gru_step(const unsigned short* __restrict__ hprev_bf,
                                                unsigned short* __restrict__ hout_bf,
                                                const unsigned short* __restrict__ Whh,
                                                const unsigned short* __restrict__ gi,
                                                const float* __restrict__ b_hh,
                                                float* __restrict__ out,
                                                int t) {
  const int blk = blockIdx.x;  // 0..255
  const int c0 = blk * 4;
  const int tid = threadIdx.x;
  const int wave = tid >> 6;
  const int lane = tid & 63;
  const int l15 = lane & 15, l4 = lane >> 4;

  // B-fragment rows: idx = l15 in [0,16); gate g = idx>>2 (3 = pad/dup), col = c0 + (idx&3)
  const int gsel = l15 >> 2;
  const int gcol = c0 + (l15 & 3);
  const long brow = (gsel < 3) ? ((long)gsel * H_ + gcol) : (long)gcol;
  const unsigned short* bptr = Whh + brow * H_ + l4 * 8;
  const unsigned short* aptr = hprev_bf + (long)(wave * 16 + l15) * H_ + l4 * 8;

  f32x4 acc0 = {}, acc1 = {}, acc2 = {}, acc3 = {};
#pragma unroll 4
  for (int kk = 0; kk < H_; kk += 128) {
    bf16x8 a0v = *(const bf16x8*)(aptr + kk);
    bf16x8 b0v = *(const bf16x8*)(bptr + kk);
    bf16x8 a1v = *(const bf16x8*)(aptr + kk + 32);
    bf16x8 b1v = *(const bf16x8*)(bptr + kk + 32);
    bf16x8 a2v = *(const bf16x8*)(aptr + kk + 64);
    bf16x8 b2v = *(const bf16x8*)(bptr + kk + 64);
    bf16x8 a3v = *(const bf16x8*)(aptr + kk + 96);
    bf16x8 b3v = *(const bf16x8*)(bptr + kk + 96);
    acc0 = __builtin_amdgcn_mfma_f32_16x16x32_bf16(a0v, b0v, acc0, 0, 0, 0);
    acc1 = __builtin_amdgcn_mfma_f32_16x16x32_bf16(a1v, b1v, acc1, 0, 0, 0);
    acc2 = __builtin_amdgcn_mfma_f32_16x16x32_bf16(a2v, b2v, acc2, 0, 0, 0);
    acc3 = __builtin_amdgcn_mfma_f32_16x16x32_bf16(a3v, b3v, acc3, 0, 0, 0);
  }
  f32x4 acc = (acc0 + acc1) + (acc2 + acc3);  // D-fragment sum == matrix sum

  // C layout: col = l15 (gate idx), row = l4*4 + r (batch within wave)
  __shared__ float gh[64][12];
  if (l15 < 12) {
#pragma unroll
    for (int r = 0; r < 4; ++r)
      gh[wave * 16 + l4 * 4 + r][l15] = acc[r];
  }
  __syncthreads();

  // gates: thread -> (batch = tid>>2, hidden col = c0 + (tid&3)); 64*4 = 256 pairs
  const int b = tid >> 2;
  const int cc = tid & 3;
  const int col = c0 + cc;
  float ghr = gh[b][cc] + b_hh[col];
  float ghz = gh[b][4 + cc] + b_hh[H_ + col];
  float ghn = gh[b][8 + cc] + b_hh[2 * H_ + col];
  const long gib = ((long)b * T_ + t) * G_;
  float gir = bf2f(gi[gib + col]);
  float giz = bf2f(gi[gib + H_ + col]);
  float gin = bf2f(gi[gib + 2 * H_ + col]);
  float hp = (t == 0) ? 0.f : out[((long)b * T_ + (t - 1)) * H_ + col];
  float rg = 1.f / (1.f + __expf(-(gir + ghr)));
  float zg = 1.f / (1.f + __expf(-(giz + ghz)));
  float pre = gin + rg * ghn;
  float ng = 2.f / (1.f + __expf(-2.f * pre)) - 1.f;  // tanh
  float hn = (1.f - zg) * ng + zg * hp;
  out[((long)b * T_ + t) * H_ + col] = hn;
  hout_bf[(long)b * H_ + col] = f2bf(hn);
}

// ---------------------------------------------------------------- launch
extern "C" void kernel_launch(void* const* d_in, const int* in_sizes, int n_in,
                              void* d_out, int out_size, void* d_ws, size_t ws_size,
                              hipStream_t stream) {
  const float* m_enc = (const float*)d_in[0];
  const float* W_ih = (const float*)d_in[1];
  const float* W_hh = (const float*)d_in[2];
  const float* b_ih = (const float*)d_in[3];
  const float* b_hh = (const float*)d_in[4];
  float* out = (float*)d_out;

  // workspace layout (bytes)
  const size_t off_A = 0;                               // M*K bf16 = 64 MiB
  const size_t off_Wih = off_A + (size_t)M_ * H_ * 2;
  const size_t off_Whh = off_Wih + (size_t)G_ * H_ * 2;
  const size_t off_gi = off_Whh + (size_t)G_ * H_ * 2;
  const size_t off_h0 = off_gi + (size_t)M_ * G_ * 2;   // gi bf16 = 192 MiB
  const size_t off_h1 = off_h0 + (size_t)B_ * H_ * 2;
  const size_t need = off_h1 + (size_t)B_ * H_ * 2;     // ~268 MiB
  if (ws_size < need) return;  // ws too small: fail loudly via wrong output

  char* ws = (char*)d_ws;
  unsigned short* A_bf = (unsigned short*)(ws + off_A);
  unsigned short* Wih_bf = (unsigned short*)(ws + off_Wih);
  unsigned short* Whh_bf = (unsigned short*)(ws + off_Whh);
  unsigned short* gi_bf = (unsigned short*)(ws + off_gi);
  unsigned short* h0 = (unsigned short*)(ws + off_h0);
  unsigned short* h1 = (unsigned short*)(ws + off_h1);

  // 1) convert inputs to bf16
  cvt_f32_to_bf16<<<(int)((size_t)M_ * H_ / 1024), 256, 0, stream>>>(m_enc, A_bf, (long)M_ * H_);
  cvt_f32_to_bf16<<<(int)((size_t)G_ * H_ / 1024), 256, 0, stream>>>(W_ih, Wih_bf, (long)G_ * H_);
  cvt_f32_to_bf16<<<(int)((size_t)G_ * H_ / 1024), 256, 0, stream>>>(W_hh, Whh_bf, (long)G_ * H_);

  // 2) gi = m_enc @ W_ih^T + b_ih   (M=32768, N=3072, K=1024)
  gemm_nt_bf16<<<(M_ / 128) * (G_ / 128), 256, 0, stream>>>(A_bf, Wih_bf, b_ih, gi_bf);

  // 3) recurrence: one launch per timestep (kernel boundary = device-wide sync)
  hipMemsetAsync(h0, 0, (size_t)B_ * H_ * 2, stream);  // h(-1) = 0, read at t=0
  for (int t = 0; t < T_; ++t) {
    unsigned short* hr = (t & 1) ? h1 : h0;
    unsigned short* hw = (t & 1) ? h0 : h1;
    gru_step<<<H_ / 4, 256, 0, stream>>>(hr, hw, Whh_bf, gi_bf, b_hh, out, t);
  }
}